// Round 17
// baseline (131.392 us; speedup 1.0000x reference)
//
#include <hip/hip_runtime.h>

// DropGCN: out = relu( mean_r( diag(k_r) A diag(k_r) X ) @ W^T + b )
//  == Y[8192,160] = A @ Xm   (Xm[:, r*32+d] = k_r .* X[:,d], bf16)
//  then per-row masked mean over the 5 replica slices, @W^T, +b, relu.
//
// Round 17: FREE-RUNNING gemm — no LDS, no barriers, ever. Each wave reads
// its Xm fragments straight from linear XmG (1 KB contiguous per wave
// instruction; 2.6 MB image is L2-resident per XCD) with register
// double-buffering (fA/fB ping-pong, 2-step unrolled loop), and its A rows
// with r13's plain scattered loads. Rationale: every synced variant r2-r16
// sits at ~4.3 TB/s while the zero-sync fill/copy kernels hit ~7; r15
// proved latency is hidden, r16 falsified DRAM-burst theory -> the last
// untested property of the fast kernels is wave self-pacing. r3 tested
// no-LDS under the nontemporal poison + tiny blocks (confounded).

#define N_NODES   8192
#define NSLICES   256          // 8192/32 K-slices
#define NCOLS     160          // 5 replicas * 32 dims
#define SLICE_US  5120         // ushorts per K-slice image (160*32)
#define MASK_WS   65536        // ws bytes reserved for normalized mask
#define KSPLIT    8
#define STEPS     (NSLICES / KSPLIT)   // 32 K-steps per block

typedef __attribute__((ext_vector_type(4))) float f32x4;
typedef __attribute__((ext_vector_type(8))) short bf16x8;

__device__ __forceinline__ unsigned short f2bf(float f) {
  // round-to-nearest-even f32 -> bf16 bits
  unsigned int u = __builtin_bit_cast(unsigned int, f);
  return (unsigned short)((u + 0x7FFFu + ((u >> 16) & 1u)) >> 16);
}

__device__ __forceinline__ unsigned pack_bf(float lo, float hi) {
  // two f32 -> packed bf16 pair (round-to-nearest ties-up; verified r3-r16)
  unsigned u0 = __builtin_bit_cast(unsigned, lo) + 0x8000u;
  unsigned u1 = __builtin_bit_cast(unsigned, hi) + 0x8000u;
  return (u1 & 0xFFFF0000u) | (u0 >> 16);
}

// ---------------------------------------------------------------------------
// prep (r8-verified, unchanged): block s handles K-slice s, all coalesced.
// LINEAR XmG layout: chunk c (16 B) = (n = c>>2, kg = c&3), kk = kg*8+e.
// ---------------------------------------------------------------------------
__global__ __launch_bounds__(256) void prep_kernel(
    const float* __restrict__ X, const void* __restrict__ raw,
    unsigned char* __restrict__ mk, unsigned short* __restrict__ XmG) {
  __shared__ float xt[32 * 33];   // [kk][d], pad 33
  __shared__ float mf[160];       // [r][kk] 0/1
  __shared__ int mode32s;
  const int tid = threadIdx.x;
  const int s = blockIdx.x;

  if (tid == 0) {
    const unsigned* wrd = (const unsigned*)raw;
    int ok = 1;
    for (int i = 0; i < 64; ++i) {
      unsigned v = wrd[i];
      if (!(v <= 1u || v == 0x3F800000u)) { ok = 0; break; }
    }
    mode32s = ok;
  }
  f32x4 xv = *(const f32x4*)(X + (size_t)s * 1024 + tid * 4);
  __syncthreads();
  const int mode32 = mode32s;
#pragma unroll
  for (int q = 0; q < 4; ++q) {
    int e = tid * 4 + q;                 // e = jj*32 + d
    xt[(e >> 5) * 33 + (e & 31)] = xv[q];
  }
  if (tid < 160) {
    int r = tid >> 5, jj = tid & 31;
    int gi = r * N_NODES + s * 32 + jj;
    unsigned char kv = mode32 ? (unsigned char)(((const unsigned*)raw)[gi] != 0u)
                              : (unsigned char)(((const unsigned char*)raw)[gi] != 0);
    mk[gi] = kv;
    mf[tid] = kv ? 1.0f : 0.0f;
  }
  __syncthreads();

  unsigned short* outp = XmG + (size_t)s * SLICE_US;
  for (int c = tid; c < 640; c += 256) {
    int n = c >> 2, kg = c & 3;          // LINEAR layout
    int r = n >> 5, d = n & 31;
    union { bf16x8 v; unsigned short us[8]; } o;
#pragma unroll
    for (int e = 0; e < 8; ++e) {
      int kk = kg * 8 + e;
      o.us[e] = f2bf(mf[r * 32 + kk] * xt[kk * 33 + d]);
    }
    *(bf16x8*)(outp + c * 8) = o.v;
  }
}

// ---------------------------------------------------------------------------
// gemm: block = 8 waves x 32 rows = 256 rows, all 160 cols, K-range 1024.
// grid (32, 8) = 256 blocks = 1/CU. NO LDS, NO BARRIERS — waves self-pace.
// Per step per wave: 10 fragment loads from XmG (1 KB contiguous each,
// L2-resident), 4 A-row loads (r13 pattern), pack, 20 MFMA. Fragments
// register-double-buffered fA/fB; A regs pack-then-reload (1-step cover).
// Fragment (lane n0,kg; elem e) <-> (n = nt*16+n0, kk = kg*8+e); same
// lane->k map on both MFMA operands (permutation cancels; r2-verified).
// Verified D map: acc[nt][jj] = Y[base_m + n0][nt*16 + kg*4 + jj].
// Fused replica mask-mean epilogue -> partZ[sy][m][d] f32.
// ---------------------------------------------------------------------------
__global__ __launch_bounds__(512, 2) void gemm_kernel(
    const float* __restrict__ A, const unsigned short* __restrict__ XmG,
    const unsigned char* __restrict__ mk, float* __restrict__ partZ) {
  const int tid  = threadIdx.x;
  const int lane = tid & 63;
  const int w    = tid >> 6;        // wave 0..7
  const int n0   = lane & 15;
  const int kg   = lane >> 4;       // k-group 0..3 (8 elems each)
  const int sy   = blockIdx.y;      // k-split 0..7
  const int s_base = sy * STEPS;
  const int base_m = blockIdx.x * 256 + w * 32;   // wave owns 32 rows

  // A rows for the wave's two 16-row tiles
  const float* aptr0 =
      A + (size_t)(base_m + n0) * N_NODES + s_base * 32 + kg * 8;
  const float* aptr1 = aptr0 + (size_t)16 * N_NODES;

  // per-lane fragment base in linear XmG (advance SLICE_US per step)
  const unsigned short* xstep =
      XmG + (size_t)s_base * SLICE_US + n0 * 32 + kg * 8;

  f32x4 acc0[10], acc1[10];
#pragma unroll
  for (int i = 0; i < 10; ++i) {
    acc0[i] = (f32x4){0.f, 0.f, 0.f, 0.f};
    acc1[i] = (f32x4){0.f, 0.f, 0.f, 0.f};
  }

  bf16x8 fA[10], fB[10];          // compile-time-indexed only (rule #20)
#pragma unroll
  for (int nt = 0; nt < 10; ++nt)
    fA[nt] = *(const bf16x8*)(xstep + nt * 512);
  f32x4 a0  = *(const f32x4*)aptr0;
  f32x4 a0b = *(const f32x4*)(aptr0 + 4);
  f32x4 a1  = *(const f32x4*)aptr1;
  f32x4 a1b = *(const f32x4*)(aptr1 + 4);

#define PACK_B(b0_, b1_)                                                       \
  b0_.u[0] = pack_bf(a0[0], a0[1]);   b0_.u[1] = pack_bf(a0[2], a0[3]);        \
  b0_.u[2] = pack_bf(a0b[0], a0b[1]); b0_.u[3] = pack_bf(a0b[2], a0b[3]);      \
  b1_.u[0] = pack_bf(a1[0], a1[1]);   b1_.u[1] = pack_bf(a1[2], a1[3]);        \
  b1_.u[2] = pack_bf(a1b[0], a1b[1]); b1_.u[3] = pack_bf(a1b[2], a1b[3]);

#define RELOAD_A(t)                                                            \
  a0  = *(const f32x4*)(aptr0 + (size_t)(t) * 32);                             \
  a0b = *(const f32x4*)(aptr0 + (size_t)(t) * 32 + 4);                         \
  a1  = *(const f32x4*)(aptr1 + (size_t)(t) * 32);                             \
  a1b = *(const f32x4*)(aptr1 + (size_t)(t) * 32 + 4);

  for (int ss = 0; ss < STEPS / 2; ++ss) {
    const int t1 = 2 * ss + 1;
    const int t2 = (2 * ss + 2 < STEPS) ? (2 * ss + 2) : t1;

    // ---- even step 2ss: compute with fA, prefetch fB (step t1)
    {
      const unsigned short* xs = xstep + (size_t)t1 * SLICE_US;
#pragma unroll
      for (int nt = 0; nt < 10; ++nt)
        fB[nt] = *(const bf16x8*)(xs + nt * 512);
      union { bf16x8 v; unsigned u[4]; } b0, b1;
      PACK_B(b0, b1);
      RELOAD_A(t1);
#pragma unroll
      for (int nt = 0; nt < 10; ++nt) {
        acc0[nt] = __builtin_amdgcn_mfma_f32_16x16x32_bf16(fA[nt], b0.v, acc0[nt], 0, 0, 0);
        acc1[nt] = __builtin_amdgcn_mfma_f32_16x16x32_bf16(fA[nt], b1.v, acc1[nt], 0, 0, 0);
      }
    }
    // ---- odd step t1: compute with fB, prefetch fA (step t2)
    {
      const unsigned short* xs = xstep + (size_t)t2 * SLICE_US;
#pragma unroll
      for (int nt = 0; nt < 10; ++nt)
        fA[nt] = *(const bf16x8*)(xs + nt * 512);
      union { bf16x8 v; unsigned u[4]; } b0, b1;
      PACK_B(b0, b1);
      RELOAD_A(t2);
#pragma unroll
      for (int nt = 0; nt < 10; ++nt) {
        acc0[nt] = __builtin_amdgcn_mfma_f32_16x16x32_bf16(fB[nt], b0.v, acc0[nt], 0, 0, 0);
        acc1[nt] = __builtin_amdgcn_mfma_f32_16x16x32_bf16(fB[nt], b1.v, acc1[nt], 0, 0, 0);
      }
    }
  }

  // fused replica mask-mean epilogue:
  // acc[2t][jj]  = Y[m][32t + kg*4+jj]       (d = kg*4+jj,    r = t)
  // acc[2t+1][jj]= Y[m][32t + 16 + kg*4+jj]  (d = kg*4+jj+16, r = t)
  const int m0g = base_m + n0;
  const int m1g = m0g + 16;
  float w0[5], w1[5];
#pragma unroll
  for (int t = 0; t < 5; ++t) {
    w0[t] = mk[t * N_NODES + m0g] ? 0.2f : 0.0f;
    w1[t] = mk[t * N_NODES + m1g] ? 0.2f : 0.0f;
  }
  f32x4 zA0 = (f32x4){0.f, 0.f, 0.f, 0.f}, zB0 = zA0, zA1 = zA0, zB1 = zA0;
#pragma unroll
  for (int t = 0; t < 5; ++t) {
    zA0 += w0[t] * acc0[2 * t];
    zB0 += w0[t] * acc0[2 * t + 1];
    zA1 += w1[t] * acc1[2 * t];
    zB1 += w1[t] * acc1[2 * t + 1];
  }
  float* p0 = partZ + ((size_t)sy * N_NODES + m0g) * 32 + kg * 4;
  *(f32x4*)(p0)      = zA0;
  *(f32x4*)(p0 + 16) = zB0;
  float* p1 = partZ + ((size_t)sy * N_NODES + m1g) * 32 + kg * 4;
  *(f32x4*)(p1)      = zA1;
  *(f32x4*)(p1 + 16) = zB1;
}

// ---------------------------------------------------------------------------
// epi: z[m][d] = sum_s partZ[s][m][d];  out[m][o] = relu(b[o] + z . W[o])
// ---------------------------------------------------------------------------
__global__ __launch_bounds__(64) void epi_kernel(
    const float* __restrict__ partZ, const float* __restrict__ W,
    const float* __restrict__ bias, float* __restrict__ out) {
  __shared__ float sW[1024];
  __shared__ float sb[32];
  const int tid = threadIdx.x;
  for (int i = tid; i < 1024; i += 64) sW[i] = W[i];
  if (tid < 32) sb[tid] = bias[tid];
  __syncthreads();

  const int m = blockIdx.x * 64 + tid;
  float zz[32];
#pragma unroll
  for (int i = 0; i < 32; ++i) zz[i] = 0.f;
  const float* p = partZ + (size_t)m * 32;
  for (int s = 0; s < KSPLIT; ++s) {
    const float* ps = p + (size_t)s * N_NODES * 32;
#pragma unroll
    for (int i = 0; i < 8; ++i) {
      f32x4 v = *(const f32x4*)(ps + i * 4);
      zz[4 * i + 0] += v[0]; zz[4 * i + 1] += v[1];
      zz[4 * i + 2] += v[2]; zz[4 * i + 3] += v[3];
    }
  }
#pragma unroll
  for (int o = 0; o < 32; o += 4) {
    f32x4 r;
#pragma unroll
    for (int q = 0; q < 4; ++q) {
      float a = sb[o + q];
#pragma unroll
      for (int d = 0; d < 32; ++d) a = fmaf(zz[d], sW[(o + q) * 32 + d], a);
      r[q] = fmaxf(a, 0.f);
    }
    *(f32x4*)(out + (size_t)m * 32 + o) = r;
  }
}

extern "C" void kernel_launch(void* const* d_in, const int* in_sizes, int n_in,
                              void* d_out, int out_size, void* d_ws, size_t ws_size,
                              hipStream_t stream) {
  const float* A = (const float*)d_in[0];
  const float* X = (const float*)d_in[1];
  const float* W = (const float*)d_in[2];
  const float* b = (const float*)d_in[3];
  const void*  keep_raw = (const void*)d_in[4];
  float* out = (float*)d_out;

  const size_t xm_bytes    = (size_t)NSLICES * SLICE_US * 2;       // 2,621,440
  const size_t partz_bytes = (size_t)KSPLIT * N_NODES * 32 * 4;    // 8,388,608
  if (ws_size < MASK_WS + xm_bytes + partz_bytes) return;  // need ~11 MB

  unsigned char* mk = (unsigned char*)d_ws;
  unsigned short* XmG = (unsigned short*)((char*)d_ws + MASK_WS);
  float* partZ = (float*)((char*)d_ws + MASK_WS + xm_bytes);

  prep_kernel<<<dim3(NSLICES), 256, 0, stream>>>(X, keep_raw, mk, XmG);
  gemm_kernel<<<dim3(N_NODES / 256, KSPLIT), 512, 0, stream>>>(A, XmG, mk, partZ);
  epi_kernel<<<dim3(N_NODES / 64), 64, 0, stream>>>(partZ, W, b, out);
}

// Round 18
// 68.102 us; speedup vs baseline: 1.9293x; 1.9293x over previous
//
#include <hip/hip_runtime.h>

// DropGCN: out = relu( mean_r( diag(k_r) A diag(k_r) X ) @ W^T + b )
//  == Y[8192,160] = A @ Xm   (Xm[:, r*32+d] = k_r .* X[:,d], bf16)
//  then per-row masked mean over the 5 replica slices, @W^T, +b, relu.
//
// Round 18: r13 champion (68.4 us) with ONE safe change: partZ stored as
// bf16 (4 MB instead of 8 MB) — halves the gemm's scattered epilogue
// writes and the epi's reads. Error budget: partials |z|<~40, bf16 eps
// ~0.13 there, through |W|<=0.43 -> <~1 absmax added vs threshold 6.08.
// Everything else byte-identical to r13 (15 structural variants tested;
// r13's shape is the measured local optimum at ~5.8 TB/s fabric).

#define N_NODES   8192
#define NSLICES   256          // 8192/32 K-slices
#define NCOLS     160          // 5 replicas * 32 dims
#define SLICE_US  5120         // ushorts per K-slice image (160*32)
#define MASK_WS   65536        // ws bytes reserved for normalized mask
#define KSPLIT    8
#define STEPS     (NSLICES / KSPLIT)   // 32 K-steps per block

typedef __attribute__((ext_vector_type(4))) float f32x4;
typedef __attribute__((ext_vector_type(2))) unsigned int uint2v;
typedef __attribute__((ext_vector_type(8))) short bf16x8;

__device__ __forceinline__ unsigned short f2bf(float f) {
  // round-to-nearest-even f32 -> bf16 bits
  unsigned int u = __builtin_bit_cast(unsigned int, f);
  return (unsigned short)((u + 0x7FFFu + ((u >> 16) & 1u)) >> 16);
}

__device__ __forceinline__ unsigned pack_bf(float lo, float hi) {
  // two f32 -> packed bf16 pair (round-to-nearest ties-up; verified r3-r17)
  unsigned u0 = __builtin_bit_cast(unsigned, lo) + 0x8000u;
  unsigned u1 = __builtin_bit_cast(unsigned, hi) + 0x8000u;
  return (u1 & 0xFFFF0000u) | (u0 >> 16);
}

__device__ __forceinline__ float bf_lo(unsigned u) {
  return __builtin_bit_cast(float, u << 16);
}
__device__ __forceinline__ float bf_hi(unsigned u) {
  return __builtin_bit_cast(float, u & 0xFFFF0000u);
}

// ---------------------------------------------------------------------------
// prep (r8-verified, unchanged): block s handles K-slice s, all coalesced.
// LINEAR XmG layout: chunk c (16 B) = (n = c>>2, kg = c&3), kk = kg*8+e.
// ---------------------------------------------------------------------------
__global__ __launch_bounds__(256) void prep_kernel(
    const float* __restrict__ X, const void* __restrict__ raw,
    unsigned char* __restrict__ mk, unsigned short* __restrict__ XmG) {
  __shared__ float xt[32 * 33];   // [kk][d], pad 33
  __shared__ float mf[160];       // [r][kk] 0/1
  __shared__ int mode32s;
  const int tid = threadIdx.x;
  const int s = blockIdx.x;

  if (tid == 0) {
    const unsigned* wrd = (const unsigned*)raw;
    int ok = 1;
    for (int i = 0; i < 64; ++i) {
      unsigned v = wrd[i];
      if (!(v <= 1u || v == 0x3F800000u)) { ok = 0; break; }
    }
    mode32s = ok;
  }
  f32x4 xv = *(const f32x4*)(X + (size_t)s * 1024 + tid * 4);
  __syncthreads();
  const int mode32 = mode32s;
#pragma unroll
  for (int q = 0; q < 4; ++q) {
    int e = tid * 4 + q;                 // e = jj*32 + d
    xt[(e >> 5) * 33 + (e & 31)] = xv[q];
  }
  if (tid < 160) {
    int r = tid >> 5, jj = tid & 31;
    int gi = r * N_NODES + s * 32 + jj;
    unsigned char kv = mode32 ? (unsigned char)(((const unsigned*)raw)[gi] != 0u)
                              : (unsigned char)(((const unsigned char*)raw)[gi] != 0);
    mk[gi] = kv;
    mf[tid] = kv ? 1.0f : 0.0f;
  }
  __syncthreads();

  unsigned short* outp = XmG + (size_t)s * SLICE_US;
  for (int c = tid; c < 640; c += 256) {
    int n = c >> 2, kg = c & 3;          // LINEAR layout
    int r = n >> 5, d = n & 31;
    union { bf16x8 v; unsigned short us[8]; } o;
#pragma unroll
    for (int e = 0; e < 8; ++e) {
      int kk = kg * 8 + e;
      o.us[e] = f2bf(mf[r * 32 + kk] * xt[kk * 33 + d]);
    }
    *(bf16x8*)(outp + c * 8) = o.v;
  }
}

// ---------------------------------------------------------------------------
// gemm (r13 structure, verbatim; epilogue writes bf16 partZ): block = 8
// waves x 32 rows = 256 rows, all 160 cols, K-range 1024. LDS double-buffer
// of one 10 KB K-slice, 1 __syncthreads/step, reg-staged with XOR swizzle:
// slice ushort (n*32+kg*8+e) at LDS ushort n*32 + ((kg ^ ((n>>1)&3))*8) + e.
// Verified D map: acc[nt][jj] = Y[base_m + n0][nt*16 + kg*4 + jj].
// Fused replica mask-mean epilogue -> partZb[sy][m][d] bf16.
// ---------------------------------------------------------------------------
__global__ __launch_bounds__(512, 2) void gemm_kernel(
    const float* __restrict__ A, const unsigned short* __restrict__ XmG,
    const unsigned char* __restrict__ mk, unsigned short* __restrict__ partZb) {
  __shared__ __align__(16) unsigned short xm[2][SLICE_US];   // 20 KB

  const int tid  = threadIdx.x;
  const int lane = tid & 63;
  const int w    = tid >> 6;        // wave 0..7
  const int n0   = lane & 15;
  const int kg   = lane >> 4;       // k-group 0..3 (8 elems each)
  const int sy   = blockIdx.y;      // k-split 0..7
  const int s_base = sy * STEPS;
  const int base_m = blockIdx.x * 256 + w * 32;   // wave owns 32 rows

  // A rows for the wave's two 16-row tiles
  const float* aptr0 =
      A + (size_t)(base_m + n0) * N_NODES + s_base * 32 + kg * 8;
  const float* aptr1 = aptr0 + (size_t)16 * N_NODES;

  // staging: thread stages chunk c0=tid (and c1=tid+512 if tid<128);
  // chunk c = 16 B at slice ushort c*8 -> n = c>>2, kgs = c&3
  const unsigned short* xsrc = XmG + (size_t)s_base * SLICE_US;
  const int c0 = tid, n_c0 = c0 >> 2;
  const int off0 = n_c0 * 32 + (((c0 & 3) ^ ((n_c0 >> 1) & 3)) << 3);
  const int c1 = tid + 512, n_c1 = c1 >> 2;
  const int off1 = n_c1 * 32 + (((c1 & 3) ^ ((n_c1 >> 1) & 3)) << 3);
  const bool has2 = (tid < 128);

  // fragment read base (swizzled slot depends only on n0,kg)
  const unsigned short* frag0 =
      &xm[0][0] + n0 * 32 + ((kg ^ ((n0 >> 1) & 3)) << 3);

  f32x4 acc0[10], acc1[10];
#pragma unroll
  for (int i = 0; i < 10; ++i) {
    acc0[i] = (f32x4){0.f, 0.f, 0.f, 0.f};
    acc1[i] = (f32x4){0.f, 0.f, 0.f, 0.f};
  }

  // prologue: slice 0 -> regs -> LDS buf0; slice 1 -> regs; A step-0 regs
  bf16x8 sa = *(const bf16x8*)(xsrc + c0 * 8);
  bf16x8 sb2 = sa;
  if (has2) sb2 = *(const bf16x8*)(xsrc + c1 * 8);
  f32x4 a0  = *(const f32x4*)aptr0;
  f32x4 a0b = *(const f32x4*)(aptr0 + 4);
  f32x4 a1  = *(const f32x4*)aptr1;
  f32x4 a1b = *(const f32x4*)(aptr1 + 4);
  *(bf16x8*)(&xm[0][off0]) = sa;
  if (has2) *(bf16x8*)(&xm[0][off1]) = sb2;
  sa = *(const bf16x8*)(xsrc + SLICE_US + c0 * 8);
  if (has2) sb2 = *(const bf16x8*)(xsrc + SLICE_US + c1 * 8);
  __syncthreads();

  int cur = 0;
  for (int step = 0; step < STEPS; ++step) {
    // stage slice step+1 into the other buffer (its prior readers finished
    // before the barrier that ended step-1)
    if (step + 1 < STEPS) {
      unsigned short* dst = &xm[cur ^ 1][0];
      *(bf16x8*)(dst + off0) = sa;
      if (has2) *(bf16x8*)(dst + off1) = sb2;
    }
    // issue global load of slice step+2 (lands during compute + barrier)
    if (step + 2 < STEPS) {
      const unsigned short* s2 = xsrc + (size_t)(step + 2) * SLICE_US;
      sa = *(const bf16x8*)(s2 + c0 * 8);
      if (has2) sb2 = *(const bf16x8*)(s2 + c1 * 8);
    }
    // prefetch next step's A registers (plain loads; r13-verified)
    const int nxt = (step + 1 < STEPS) ? (step + 1) : step;
    f32x4 na0  = *(const f32x4*)(aptr0 + (size_t)nxt * 32);
    f32x4 na0b = *(const f32x4*)(aptr0 + (size_t)nxt * 32 + 4);
    f32x4 na1  = *(const f32x4*)(aptr1 + (size_t)nxt * 32);
    f32x4 na1b = *(const f32x4*)(aptr1 + (size_t)nxt * 32 + 4);

    // pack B fragments (same lane->k map as A-op; permutation cancels)
    union { bf16x8 v; unsigned u[4]; } b0, b1;
    b0.u[0] = pack_bf(a0[0], a0[1]);   b0.u[1] = pack_bf(a0[2], a0[3]);
    b0.u[2] = pack_bf(a0b[0], a0b[1]); b0.u[3] = pack_bf(a0b[2], a0b[3]);
    b1.u[0] = pack_bf(a1[0], a1[1]);   b1.u[1] = pack_bf(a1[2], a1[3]);
    b1.u[2] = pack_bf(a1b[0], a1b[1]); b1.u[3] = pack_bf(a1b[2], a1b[3]);

    const unsigned short* fb = frag0 + cur * SLICE_US;
#pragma unroll
    for (int nt = 0; nt < 10; ++nt) {
      bf16x8 af = *(const bf16x8*)(fb + nt * 512);
      acc0[nt] = __builtin_amdgcn_mfma_f32_16x16x32_bf16(af, b0.v, acc0[nt], 0, 0, 0);
      acc1[nt] = __builtin_amdgcn_mfma_f32_16x16x32_bf16(af, b1.v, acc1[nt], 0, 0, 0);
    }
    __syncthreads();   // reads of buf[cur] done; buf[cur^1] writes visible
    cur ^= 1;
    a0 = na0; a0b = na0b; a1 = na1; a1b = na1b;
  }

  // fused replica mask-mean epilogue (bf16 partials):
  // acc[2t][jj]  = Y[m][32t + kg*4+jj]       (d = kg*4+jj,    r = t)
  // acc[2t+1][jj]= Y[m][32t + 16 + kg*4+jj]  (d = kg*4+jj+16, r = t)
  const int m0g = base_m + n0;
  const int m1g = m0g + 16;
  float w0[5], w1[5];
#pragma unroll
  for (int t = 0; t < 5; ++t) {
    w0[t] = mk[t * N_NODES + m0g] ? 0.2f : 0.0f;
    w1[t] = mk[t * N_NODES + m1g] ? 0.2f : 0.0f;
  }
  f32x4 zA0 = (f32x4){0.f, 0.f, 0.f, 0.f}, zB0 = zA0, zA1 = zA0, zB1 = zA0;
#pragma unroll
  for (int t = 0; t < 5; ++t) {
    zA0 += w0[t] * acc0[2 * t];
    zB0 += w0[t] * acc0[2 * t + 1];
    zA1 += w1[t] * acc1[2 * t];
    zB1 += w1[t] * acc1[2 * t + 1];
  }
  // partZb[sy][m][d] (ushort): lane writes d = kg*4..+3 and +16 (8 B each)
  unsigned short* p0 = partZb + ((size_t)sy * N_NODES + m0g) * 32 + kg * 4;
  uint2v v;
  v[0] = pack_bf(zA0[0], zA0[1]); v[1] = pack_bf(zA0[2], zA0[3]);
  *(uint2v*)(p0) = v;
  v[0] = pack_bf(zB0[0], zB0[1]); v[1] = pack_bf(zB0[2], zB0[3]);
  *(uint2v*)(p0 + 16) = v;
  unsigned short* p1 = partZb + ((size_t)sy * N_NODES + m1g) * 32 + kg * 4;
  v[0] = pack_bf(zA1[0], zA1[1]); v[1] = pack_bf(zA1[2], zA1[3]);
  *(uint2v*)(p1) = v;
  v[0] = pack_bf(zB1[0], zB1[1]); v[1] = pack_bf(zB1[2], zB1[3]);
  *(uint2v*)(p1 + 16) = v;
}

// ---------------------------------------------------------------------------
// epi: z[m][d] = sum_s bf16(partZb[s][m][d]);  out = relu(b + z . W^T)
// ---------------------------------------------------------------------------
__global__ __launch_bounds__(64) void epi_kernel(
    const unsigned short* __restrict__ partZb, const float* __restrict__ W,
    const float* __restrict__ bias, float* __restrict__ out) {
  __shared__ float sW[1024];
  __shared__ float sb[32];
  const int tid = threadIdx.x;
  for (int i = tid; i < 1024; i += 64) sW[i] = W[i];
  if (tid < 32) sb[tid] = bias[tid];
  __syncthreads();

  const int m = blockIdx.x * 64 + tid;
  float zz[32];
#pragma unroll
  for (int i = 0; i < 32; ++i) zz[i] = 0.f;
  const unsigned* p = (const unsigned*)(partZb + (size_t)m * 32);
  for (int s = 0; s < KSPLIT; ++s) {
    const unsigned* ps = p + (size_t)s * N_NODES * 16;   // 16 uints = 32 bf16
#pragma unroll
    for (int i = 0; i < 4; ++i) {
      uint2v v0 = *(const uint2v*)(ps + i * 4);
      uint2v v1 = *(const uint2v*)(ps + i * 4 + 2);
      zz[8 * i + 0] += bf_lo(v0[0]); zz[8 * i + 1] += bf_hi(v0[0]);
      zz[8 * i + 2] += bf_lo(v0[1]); zz[8 * i + 3] += bf_hi(v0[1]);
      zz[8 * i + 4] += bf_lo(v1[0]); zz[8 * i + 5] += bf_hi(v1[0]);
      zz[8 * i + 6] += bf_lo(v1[1]); zz[8 * i + 7] += bf_hi(v1[1]);
    }
  }
#pragma unroll
  for (int o = 0; o < 32; o += 4) {
    f32x4 r;
#pragma unroll
    for (int q = 0; q < 4; ++q) {
      float a = sb[o + q];
#pragma unroll
      for (int d = 0; d < 32; ++d) a = fmaf(zz[d], sW[(o + q) * 32 + d], a);
      r[q] = fmaxf(a, 0.f);
    }
    *(f32x4*)(out + (size_t)m * 32 + o) = r;
  }
}

extern "C" void kernel_launch(void* const* d_in, const int* in_sizes, int n_in,
                              void* d_out, int out_size, void* d_ws, size_t ws_size,
                              hipStream_t stream) {
  const float* A = (const float*)d_in[0];
  const float* X = (const float*)d_in[1];
  const float* W = (const float*)d_in[2];
  const float* b = (const float*)d_in[3];
  const void*  keep_raw = (const void*)d_in[4];
  float* out = (float*)d_out;

  const size_t xm_bytes    = (size_t)NSLICES * SLICE_US * 2;       // 2,621,440
  const size_t partz_bytes = (size_t)KSPLIT * N_NODES * 32 * 2;    // 4,194,304
  if (ws_size < MASK_WS + xm_bytes + partz_bytes) return;  // need ~6.9 MB

  unsigned char* mk = (unsigned char*)d_ws;
  unsigned short* XmG = (unsigned short*)((char*)d_ws + MASK_WS);
  unsigned short* partZb = (unsigned short*)((char*)d_ws + MASK_WS + xm_bytes);

  prep_kernel<<<dim3(NSLICES), 256, 0, stream>>>(X, keep_raw, mk, XmG);
  gemm_kernel<<<dim3(N_NODES / 256, KSPLIT), 512, 0, stream>>>(A, XmG, mk, partZb);
  epi_kernel<<<dim3(N_NODES / 64), 64, 0, stream>>>(partZb, W, b, out);
}